// Round 1
// baseline (523.757 us; speedup 1.0000x reference)
//
#include <hip/hip_runtime.h>
#include <cstdint>
#include <cstddef>

#define S_LEN 2048
#define DM    4096
#define NH    32
#define NKV   8
#define HDIM  128
#define EQ    4096   // NH*HDIM
#define EKV   1024   // NKV*HDIM
#define SCALE 0.08838834764831845f

typedef unsigned short u16;
typedef short bf16x8 __attribute__((ext_vector_type(8)));
typedef float f32x4  __attribute__((ext_vector_type(4)));

__device__ __forceinline__ u16 f2bf(float f) {
  union { float f; unsigned u; } v; v.f = f;
  unsigned r = v.u + 0x7FFFu + ((v.u >> 16) & 1u);
  return (u16)(r >> 16);
}
__device__ __forceinline__ float bf2f(u16 b) {
  union { unsigned u; float f; } v; v.u = ((unsigned)b) << 16;
  return v.f;
}
__device__ __forceinline__ void glds16(const void* g, void* l) {
  __builtin_amdgcn_global_load_lds((const __attribute__((address_space(1))) void*)g,
                                   (__attribute__((address_space(3))) void*)l, 16, 0, 0);
}

// ---------------------------------------------------------------- cast fp32->bf16
// x (8.4M), wq (16.8M), wk (4.2M), wv (4.2M), wo (16.8M): 12582912 float4-units
__global__ void cast_all(const float* __restrict__ x, const float* __restrict__ wq,
                         const float* __restrict__ wk, const float* __restrict__ wv,
                         const float* __restrict__ wo,
                         u16* __restrict__ xb, u16* __restrict__ wqb,
                         u16* __restrict__ wkb, u16* __restrict__ wvb,
                         u16* __restrict__ wob) {
  const size_t stride = (size_t)gridDim.x * blockDim.x;
  for (size_t u = (size_t)blockIdx.x * blockDim.x + threadIdx.x; u < 12582912u; u += stride) {
    const float* in; u16* outp; size_t i;
    if (u < 2097152u)      { in = x;  outp = xb;  i = u; }
    else if (u < 6291456u) { in = wq; outp = wqb; i = u - 2097152u; }
    else if (u < 7340032u) { in = wk; outp = wkb; i = u - 6291456u; }
    else if (u < 8388608u) { in = wv; outp = wvb; i = u - 7340032u; }
    else                   { in = wo; outp = wob; i = u - 8388608u; }
    float4 f = ((const float4*)in)[i];
    ushort4 b;
    b.x = f2bf(f.x); b.y = f2bf(f.y); b.z = f2bf(f.z); b.w = f2bf(f.w);
    ((ushort4*)outp)[i] = b;
  }
}

// ---------------------------------------------------------------- GEMM C = A * B^T
// A[M,K], B[N,K] bf16 row-major; C[M,N] bf16 or fp32. 128x128 tile, BK=32,
// 4 waves in 2x2, global_load_lds width-16 staging (m97 structure).
template<bool OUT_BF16>
__global__ __launch_bounds__(256, 2)
void gemm_nt(const u16* __restrict__ A, const u16* __restrict__ B,
             void* __restrict__ Cptr, int M, int N, int K) {
  __shared__ u16 lA[128 * 32];
  __shared__ u16 lB[128 * 32];
  const int t = threadIdx.x;
  const int l = t & 63;
  const int lr = l & 15, lg = l >> 4;
  const int wb = t & ~63;
  const int m0 = blockIdx.y * 128, n0 = blockIdx.x * 128;
  const int wr = ((t >> 6) >> 1) * 64, wc = ((t >> 6) & 1) * 64;

  f32x4 acc[4][4] = {};

  for (int k0 = 0; k0 < K; k0 += 32) {
    __syncthreads();
#pragma unroll
    for (int h = 0; h < 2; ++h) {
      const int f = h * 256 + t;
      const int row = f >> 2, u = f & 3;
      glds16(A + (size_t)(m0 + row) * K + k0 + u * 8, &lA[(h * 256 + wb) * 8]);
    }
#pragma unroll
    for (int h = 0; h < 2; ++h) {
      const int f = h * 256 + t;
      const int row = f >> 2, u = f & 3;
      glds16(B + (size_t)(n0 + row) * K + k0 + u * 8, &lB[(h * 256 + wb) * 8]);
    }
    __syncthreads();
    bf16x8 af[4], bfr[4];
#pragma unroll
    for (int m = 0; m < 4; ++m)
      af[m] = *(const bf16x8*)&lA[(wr + m * 16 + lr) * 32 + lg * 8];
#pragma unroll
    for (int n = 0; n < 4; ++n)
      bfr[n] = *(const bf16x8*)&lB[(wc + n * 16 + lr) * 32 + lg * 8];
#pragma unroll
    for (int m = 0; m < 4; ++m)
#pragma unroll
      for (int n = 0; n < 4; ++n)
        acc[m][n] = __builtin_amdgcn_mfma_f32_16x16x32_bf16(af[m], bfr[n], acc[m][n], 0, 0, 0);
  }

#pragma unroll
  for (int m = 0; m < 4; ++m)
#pragma unroll
    for (int n = 0; n < 4; ++n)
#pragma unroll
      for (int r = 0; r < 4; ++r) {
        const int row = m0 + wr + m * 16 + lg * 4 + r;
        const int col = n0 + wc + n * 16 + lr;
        if constexpr (OUT_BF16)
          ((u16*)Cptr)[(size_t)row * N + col] = f2bf(acc[m][n][r]);
        else
          ((float*)Cptr)[(size_t)row * N + col] = acc[m][n][r];
      }
}

// ---------------------------------------------------------------- RoPE (q then k)
// unit = 8 bf16 (4 pairs). q: S*NH*16 = 1048576 units; k: S*NKV*16 = 262144.
__global__ void rope_all(u16* __restrict__ qd, u16* __restrict__ kd,
                         const float* __restrict__ cosb, const float* __restrict__ sinb,
                         const int* __restrict__ sidx) {
  const int u = blockIdx.x * blockDim.x + threadIdx.x;
  u16* base; int s, b;
  if (u < 1048576) {
    base = qd + (size_t)u * 8;
    s = u >> 9;          // (u>>4)/NH
    b = u & 15;
  } else if (u < 1310720) {
    const int u2 = u - 1048576;
    base = kd + (size_t)u2 * 8;
    s = u2 >> 7;         // (u2>>4)/NKV
    b = u2 & 15;
  } else return;
  const int pos = sidx[s];
  const float4 c  = *(const float4*)&cosb[pos * 64 + b * 4];
  const float4 sn = *(const float4*)&sinb[pos * 64 + b * 4];
  uint4 raw = *(uint4*)base;
  u16* pe = (u16*)&raw;
  const float cc[4] = {c.x, c.y, c.z, c.w};
  const float ss[4] = {sn.x, sn.y, sn.z, sn.w};
#pragma unroll
  for (int j = 0; j < 4; ++j) {
    const float xr = bf2f(pe[2 * j]), xi = bf2f(pe[2 * j + 1]);
    pe[2 * j]     = f2bf(xr * cc[j] - xi * ss[j]);
    pe[2 * j + 1] = f2bf(xr * ss[j] + xi * cc[j]);
  }
  *(uint4*)base = raw;
}

// ---------------------------------------------------------------- V transpose
// v[S, EKV] -> vt[EKV, S]
__global__ void transpose_v(const u16* __restrict__ v, u16* __restrict__ vt) {
  __shared__ u16 tile[32][33];
  const int tx = threadIdx.x, ty = threadIdx.y;
  const int c0 = blockIdx.x * 32, s0 = blockIdx.y * 32;
#pragma unroll
  for (int j = 0; j < 32; j += 8)
    tile[ty + j][tx] = v[(size_t)(s0 + ty + j) * EKV + c0 + tx];
  __syncthreads();
#pragma unroll
  for (int j = 0; j < 32; j += 8)
    vt[(size_t)(c0 + ty + j) * S_LEN + s0 + tx] = tile[tx][ty + j];
}

// ---------------------------------------------------------------- flash attention
// block = 4 waves x 32 q-rows = 128 q rows, one head. KVBLK=64.
// K tile [64][128] and Vt tile [128][64] staged via glds with pre-swizzled
// global source (XOR u ^= row&7 on 16B units); reads apply the same XOR.
__global__ __launch_bounds__(256, 2)
void attn_fwd(const u16* __restrict__ q, const u16* __restrict__ k,
              const u16* __restrict__ vt, u16* __restrict__ ao) {
  __shared__ u16 lK[64 * 128];
  __shared__ u16 lV[128 * 64];
  __shared__ u16 lP[4 * 32 * 72];
  const int t = threadIdx.x, w = t >> 6, l = t & 63;
  const int lr = l & 15, lg = l >> 4;
  const int wb = t & ~63;
  const int qblk = blockIdx.x, h = blockIdx.y;
  const int kvh = h >> 2;                    // GQA: head h -> kv head h/4
  const int q0 = qblk * 128 + w * 32;
  u16* lPw = &lP[w * (32 * 72)];

  bf16x8 qa[2][4];
#pragma unroll
  for (int m = 0; m < 2; ++m)
#pragma unroll
    for (int kc = 0; kc < 4; ++kc)
      qa[m][kc] = *(const bf16x8*)&q[(size_t)(q0 + m * 16 + lr) * EQ + h * HDIM + kc * 32 + lg * 8];

  f32x4 o[2][8] = {};
  float mrun[2][4], lrun[2][4];
#pragma unroll
  for (int m = 0; m < 2; ++m)
#pragma unroll
    for (int r = 0; r < 4; ++r) { mrun[m][r] = -1e30f; lrun[m][r] = 0.f; }

  const int ntiles = qblk * 2 + 2;
  for (int tk = 0; tk < ntiles; ++tk) {
    const int kv0 = tk * 64;
    __syncthreads();
#pragma unroll
    for (int hh = 0; hh < 4; ++hh) {
      const int f = hh * 256 + t;
      { const int row = f >> 4, u = f & 15, us = u ^ (row & 7);
        glds16(&k[(size_t)(kv0 + row) * EKV + kvh * HDIM + us * 8], &lK[(hh * 256 + wb) * 8]); }
      { const int row = f >> 3, u = f & 7, us = u ^ (row & 7);
        glds16(&vt[(size_t)(kvh * HDIM + row) * S_LEN + kv0 + us * 8], &lV[(hh * 256 + wb) * 8]); }
    }
    __syncthreads();

    // S = Q K^T  (32q x 64kv per wave)
    f32x4 sc[2][4] = {};
#pragma unroll
    for (int n = 0; n < 4; ++n) {
#pragma unroll
      for (int kc = 0; kc < 4; ++kc) {
        const int row = n * 16 + lr;
        const int us = (kc * 4 + lg) ^ (row & 7);
        bf16x8 bk = *(const bf16x8*)&lK[row * 128 + us * 8];
#pragma unroll
        for (int m = 0; m < 2; ++m)
          sc[m][n] = __builtin_amdgcn_mfma_f32_16x16x32_bf16(qa[m][kc], bk, sc[m][n], 0, 0, 0);
      }
    }

    // online softmax (rows live on lanes sharing lg; reduce over 16 lanes lr)
#pragma unroll
    for (int m = 0; m < 2; ++m) {
#pragma unroll
      for (int n = 0; n < 4; ++n) {
        const int kvc = kv0 + n * 16 + lr;
#pragma unroll
        for (int r = 0; r < 4; ++r) {
          const int qr = q0 + m * 16 + lg * 4 + r;
          const float v = sc[m][n][r] * SCALE;
          sc[m][n][r] = (kvc > qr) ? -1e30f : v;
        }
      }
#pragma unroll
      for (int r = 0; r < 4; ++r) {
        float v = fmaxf(fmaxf(sc[m][0][r], sc[m][1][r]), fmaxf(sc[m][2][r], sc[m][3][r]));
        v = fmaxf(v, __shfl_xor(v, 1));
        v = fmaxf(v, __shfl_xor(v, 2));
        v = fmaxf(v, __shfl_xor(v, 4));
        v = fmaxf(v, __shfl_xor(v, 8));
        const float mn = fmaxf(mrun[m][r], v);
        const float sf = __expf(mrun[m][r] - mn);
        mrun[m][r] = mn;
        float rs = 0.f;
#pragma unroll
        for (int n = 0; n < 4; ++n) {
          const float p = __expf(sc[m][n][r] - mn);
          sc[m][n][r] = p;
          rs += p;
        }
        rs += __shfl_xor(rs, 1);
        rs += __shfl_xor(rs, 2);
        rs += __shfl_xor(rs, 4);
        rs += __shfl_xor(rs, 8);
        lrun[m][r] = lrun[m][r] * sf + rs;
#pragma unroll
        for (int nh = 0; nh < 8; ++nh) o[m][nh][r] *= sf;
      }
      // P (C-layout) -> per-wave LDS, padded stride 72 (bank-friendly)
#pragma unroll
      for (int n = 0; n < 4; ++n)
#pragma unroll
        for (int r = 0; r < 4; ++r)
          lPw[(m * 16 + lg * 4 + r) * 72 + n * 16 + lr] = f2bf(sc[m][n][r]);
    }

    // O += P V
#pragma unroll
    for (int kc2 = 0; kc2 < 2; ++kc2) {
      bf16x8 pa[2];
#pragma unroll
      for (int m = 0; m < 2; ++m)
        pa[m] = *(const bf16x8*)&lPw[(m * 16 + lr) * 72 + kc2 * 32 + lg * 8];
#pragma unroll
      for (int nh = 0; nh < 8; ++nh) {
        const int row = nh * 16 + lr;
        const int us = (kc2 * 4 + lg) ^ (row & 7);
        bf16x8 bv = *(const bf16x8*)&lV[row * 64 + us * 8];
#pragma unroll
        for (int m = 0; m < 2; ++m)
          o[m][nh] = __builtin_amdgcn_mfma_f32_16x16x32_bf16(pa[m], bv, o[m][nh], 0, 0, 0);
      }
    }
  }

#pragma unroll
  for (int m = 0; m < 2; ++m)
#pragma unroll
    for (int nh = 0; nh < 8; ++nh)
#pragma unroll
      for (int r = 0; r < 4; ++r) {
        const float val = o[m][nh][r] / lrun[m][r];
        ao[(size_t)(q0 + m * 16 + lg * 4 + r) * EQ + h * HDIM + nh * 16 + lr] = f2bf(val);
      }
}

// ---------------------------------------------------------------- launch
extern "C" void kernel_launch(void* const* d_in, const int* in_sizes, int n_in,
                              void* d_out, int out_size, void* d_ws, size_t ws_size,
                              hipStream_t stream) {
  (void)in_sizes; (void)n_in; (void)out_size; (void)ws_size;
  const float* x    = (const float*)d_in[0];
  const float* wq   = (const float*)d_in[1];
  const float* wk   = (const float*)d_in[2];
  const float* wv   = (const float*)d_in[3];
  const float* wo   = (const float*)d_in[4];
  const float* cosb = (const float*)d_in[7];
  const float* sinb = (const float*)d_in[8];
  const int*   sidx = (const int*)d_in[10];
  float* out = (float*)d_out;

  u16* ws  = (u16*)d_ws;
  u16* xb  = ws;                                  // 2048*4096
  u16* wqb = xb  + (size_t)S_LEN * DM;            // 4096*4096
  u16* wkb = wqb + (size_t)EQ * DM;               // 1024*4096
  u16* wvb = wkb + (size_t)EKV * DM;              // 1024*4096
  u16* wob = wvb + (size_t)EKV * DM;              // 4096*4096
  u16* qb  = wob + (size_t)DM * EQ;               // 2048*4096
  u16* kb  = qb  + (size_t)S_LEN * EQ;            // 2048*1024
  u16* vb  = kb  + (size_t)S_LEN * EKV;           // 2048*1024
  u16* vtb = vb  + (size_t)S_LEN * EKV;           // 1024*2048
  u16* aob = vtb + (size_t)S_LEN * EKV;           // 2048*4096

  cast_all<<<2048, 256, 0, stream>>>(x, wq, wk, wv, wo, xb, wqb, wkb, wvb, wob);
  gemm_nt<true><<<dim3(EQ / 128, S_LEN / 128), 256, 0, stream>>>(xb, wqb, qb, S_LEN, EQ, DM);
  gemm_nt<true><<<dim3(EKV / 128, S_LEN / 128), 256, 0, stream>>>(xb, wkb, kb, S_LEN, EKV, DM);
  gemm_nt<true><<<dim3(EKV / 128, S_LEN / 128), 256, 0, stream>>>(xb, wvb, vb, S_LEN, EKV, DM);
  rope_all<<<5120, 256, 0, stream>>>(qb, kb, cosb, sinb, sidx);
  transpose_v<<<dim3(EKV / 32, S_LEN / 32), dim3(32, 8), 0, stream>>>(vb, vtb);
  attn_fwd<<<dim3(S_LEN / 128, NH), 256, 0, stream>>>(qb, kb, vtb, aob);
  gemm_nt<false><<<dim3(DM / 128, S_LEN / 128), 256, 0, stream>>>(aob, wob, out, S_LEN, DM, EQ);
}

// Round 2
// 479.134 us; speedup vs baseline: 1.0931x; 1.0931x over previous
//
#include <hip/hip_runtime.h>
#include <cstdint>
#include <cstddef>

#define S_LEN 2048
#define DM    4096
#define NH    32
#define NKV   8
#define HDIM  128
#define EQ    4096   // NH*HDIM
#define EKV   1024   // NKV*HDIM
#define SCALE 0.08838834764831845f
#define SC_LOG2E 0.1275325477889277f   // SCALE * log2(e)

typedef unsigned short u16;
typedef short bf16x8 __attribute__((ext_vector_type(8)));
typedef float f32x4  __attribute__((ext_vector_type(4)));

__device__ __forceinline__ u16 f2bf(float f) {
  union { float f; unsigned u; } v; v.f = f;
  unsigned r = v.u + 0x7FFFu + ((v.u >> 16) & 1u);
  return (u16)(r >> 16);
}
__device__ __forceinline__ float bf2f(u16 b) {
  union { unsigned u; float f; } v; v.u = ((unsigned)b) << 16;
  return v.f;
}
__device__ __forceinline__ void glds16(const void* g, void* l) {
  __builtin_amdgcn_global_load_lds((const __attribute__((address_space(1))) void*)g,
                                   (__attribute__((address_space(3))) void*)l, 16, 0, 0);
}

// ---------------------------------------------------------------- cast fp32->bf16
__global__ void cast_all(const float* __restrict__ x, const float* __restrict__ wq,
                         const float* __restrict__ wk, const float* __restrict__ wv,
                         const float* __restrict__ wo,
                         u16* __restrict__ xb, u16* __restrict__ wqb,
                         u16* __restrict__ wkb, u16* __restrict__ wvb,
                         u16* __restrict__ wob) {
  const size_t stride = (size_t)gridDim.x * blockDim.x;
  for (size_t u = (size_t)blockIdx.x * blockDim.x + threadIdx.x; u < 12582912u; u += stride) {
    const float* in; u16* outp; size_t i;
    if (u < 2097152u)      { in = x;  outp = xb;  i = u; }
    else if (u < 6291456u) { in = wq; outp = wqb; i = u - 2097152u; }
    else if (u < 7340032u) { in = wk; outp = wkb; i = u - 6291456u; }
    else if (u < 8388608u) { in = wv; outp = wvb; i = u - 7340032u; }
    else                   { in = wo; outp = wob; i = u - 8388608u; }
    float4 f = ((const float4*)in)[i];
    ushort4 b;
    b.x = f2bf(f.x); b.y = f2bf(f.y); b.z = f2bf(f.z); b.w = f2bf(f.w);
    ((ushort4*)outp)[i] = b;
  }
}

// ---------------------------------------------------------------- GEMM C = A * B^T
template<bool OUT_BF16>
__global__ __launch_bounds__(256, 2)
void gemm_nt(const u16* __restrict__ A, const u16* __restrict__ B,
             void* __restrict__ Cptr, int M, int N, int K) {
  __shared__ u16 lA[128 * 32];
  __shared__ u16 lB[128 * 32];
  const int t = threadIdx.x;
  const int l = t & 63;
  const int lr = l & 15, lg = l >> 4;
  const int wb = t & ~63;
  const int m0 = blockIdx.y * 128, n0 = blockIdx.x * 128;
  const int wr = ((t >> 6) >> 1) * 64, wc = ((t >> 6) & 1) * 64;

  f32x4 acc[4][4] = {};

  for (int k0 = 0; k0 < K; k0 += 32) {
    __syncthreads();
#pragma unroll
    for (int h = 0; h < 2; ++h) {
      const int f = h * 256 + t;
      const int row = f >> 2, u = f & 3;
      glds16(A + (size_t)(m0 + row) * K + k0 + u * 8, &lA[(h * 256 + wb) * 8]);
    }
#pragma unroll
    for (int h = 0; h < 2; ++h) {
      const int f = h * 256 + t;
      const int row = f >> 2, u = f & 3;
      glds16(B + (size_t)(n0 + row) * K + k0 + u * 8, &lB[(h * 256 + wb) * 8]);
    }
    __syncthreads();
    bf16x8 af[4], bfr[4];
#pragma unroll
    for (int m = 0; m < 4; ++m)
      af[m] = *(const bf16x8*)&lA[(wr + m * 16 + lr) * 32 + lg * 8];
#pragma unroll
    for (int n = 0; n < 4; ++n)
      bfr[n] = *(const bf16x8*)&lB[(wc + n * 16 + lr) * 32 + lg * 8];
#pragma unroll
    for (int m = 0; m < 4; ++m)
#pragma unroll
      for (int n = 0; n < 4; ++n)
        acc[m][n] = __builtin_amdgcn_mfma_f32_16x16x32_bf16(af[m], bfr[n], acc[m][n], 0, 0, 0);
  }

#pragma unroll
  for (int m = 0; m < 4; ++m)
#pragma unroll
    for (int n = 0; n < 4; ++n)
#pragma unroll
      for (int r = 0; r < 4; ++r) {
        const int row = m0 + wr + m * 16 + lg * 4 + r;
        const int col = n0 + wc + n * 16 + lr;
        if constexpr (OUT_BF16)
          ((u16*)Cptr)[(size_t)row * N + col] = f2bf(acc[m][n][r]);
        else
          ((float*)Cptr)[(size_t)row * N + col] = acc[m][n][r];
      }
}

// ---------------------------------------------------------------- RoPE (q then k)
__global__ void rope_all(u16* __restrict__ qd, u16* __restrict__ kd,
                         const float* __restrict__ cosb, const float* __restrict__ sinb,
                         const int* __restrict__ sidx) {
  const int u = blockIdx.x * blockDim.x + threadIdx.x;
  u16* base; int s, b;
  if (u < 1048576) {
    base = qd + (size_t)u * 8;
    s = u >> 9;
    b = u & 15;
  } else if (u < 1310720) {
    const int u2 = u - 1048576;
    base = kd + (size_t)u2 * 8;
    s = u2 >> 7;
    b = u2 & 15;
  } else return;
  const int pos = sidx[s];
  const float4 c  = *(const float4*)&cosb[pos * 64 + b * 4];
  const float4 sn = *(const float4*)&sinb[pos * 64 + b * 4];
  uint4 raw = *(uint4*)base;
  u16* pe = (u16*)&raw;
  const float cc[4] = {c.x, c.y, c.z, c.w};
  const float ss[4] = {sn.x, sn.y, sn.z, sn.w};
#pragma unroll
  for (int j = 0; j < 4; ++j) {
    const float xr = bf2f(pe[2 * j]), xi = bf2f(pe[2 * j + 1]);
    pe[2 * j]     = f2bf(xr * cc[j] - xi * ss[j]);
    pe[2 * j + 1] = f2bf(xr * ss[j] + xi * cc[j]);
  }
  *(uint4*)base = raw;
}

// ---------------------------------------------------------------- V transpose
__global__ void transpose_v(const u16* __restrict__ v, u16* __restrict__ vt) {
  __shared__ u16 tile[32][33];
  const int tx = threadIdx.x, ty = threadIdx.y;
  const int c0 = blockIdx.x * 32, s0 = blockIdx.y * 32;
#pragma unroll
  for (int j = 0; j < 32; j += 8)
    tile[ty + j][tx] = v[(size_t)(s0 + ty + j) * EKV + c0 + tx];
  __syncthreads();
#pragma unroll
  for (int j = 0; j < 32; j += 8)
    vt[(size_t)(c0 + ty + j) * S_LEN + s0 + tx] = tile[tx][ty + j];
}

// ---------------------------------------------------------------- flash attention
// Causal-pairing for perfect load balance: block (p, h) processes q-tile p
// then q-tile 31-p (64 rows each); work = (p+1)+(32-p) = 33 KV-tiles for
// every block. 512 blocks -> 2 balanced blocks/CU. 4 waves x 16 q-rows.
// K [64][128] / Vt [128][64] staged via glds with pre-swizzled global source
// (u ^= row&7 on 16B units); reads apply the same XOR. Softmax in exp2 domain.
__global__ __launch_bounds__(256, 2)
void attn_fwd(const u16* __restrict__ q, const u16* __restrict__ k,
              const u16* __restrict__ vt, u16* __restrict__ ao) {
  __shared__ u16 lK[64 * 128];
  __shared__ u16 lV[128 * 64];
  __shared__ u16 lP[4 * 16 * 72];
  const int t = threadIdx.x, w = t >> 6, l = t & 63;
  const int lr = l & 15, lg = l >> 4;
  const int wb = t & ~63;
  const int p = blockIdx.x, h = blockIdx.y;
  const int kvh = h >> 2;                    // GQA: head h -> kv head h/4
  u16* lPw = &lP[w * (16 * 72)];

#pragma unroll 1
  for (int ph = 0; ph < 2; ++ph) {
    const int qt = ph ? (31 - p) : p;       // q-tile index (64 rows)
    const int q0 = qt * 64 + w * 16;        // this wave's first q row
    const int nt = qt + 1;                  // causal KV-tile count

    bf16x8 qa[4];
#pragma unroll
    for (int kc = 0; kc < 4; ++kc)
      qa[kc] = *(const bf16x8*)&q[(size_t)(q0 + lr) * EQ + h * HDIM + kc * 32 + lg * 8];

    f32x4 o[8] = {};
    float mrun[4], lrun[4];
#pragma unroll
    for (int r = 0; r < 4; ++r) { mrun[r] = -1e30f; lrun[r] = 0.f; }

    for (int tk = 0; tk < nt; ++tk) {
      const int kv0 = tk * 64;
      __syncthreads();
#pragma unroll
      for (int hh = 0; hh < 4; ++hh) {
        const int f = hh * 256 + t;
        { const int row = f >> 4, u = f & 15, us = u ^ (row & 7);
          glds16(&k[(size_t)(kv0 + row) * EKV + kvh * HDIM + us * 8], &lK[(hh * 256 + wb) * 8]); }
        { const int row = f >> 3, u = f & 7, us = u ^ (row & 7);
          glds16(&vt[(size_t)(kvh * HDIM + row) * S_LEN + kv0 + us * 8], &lV[(hh * 256 + wb) * 8]); }
      }
      __syncthreads();

      // S = Q K^T  (16q x 64kv per wave)
      f32x4 sc[4] = {};
#pragma unroll
      for (int n = 0; n < 4; ++n) {
#pragma unroll
        for (int kc = 0; kc < 4; ++kc) {
          const int row = n * 16 + lr;
          const int us = (kc * 4 + lg) ^ (row & 7);
          bf16x8 bk = *(const bf16x8*)&lK[row * 128 + us * 8];
          sc[n] = __builtin_amdgcn_mfma_f32_16x16x32_bf16(qa[kc], bk, sc[n], 0, 0, 0);
        }
      }

      // mask + scale into log2 domain
#pragma unroll
      for (int n = 0; n < 4; ++n) {
        const int kvc = kv0 + n * 16 + lr;
#pragma unroll
        for (int r = 0; r < 4; ++r) {
          const int qr = q0 + lg * 4 + r;
          const float v = sc[n][r] * SC_LOG2E;
          sc[n][r] = (kvc > qr) ? -1e30f : v;
        }
      }
      // online softmax (rows on lanes sharing lg; reduce over 16 lanes lr)
#pragma unroll
      for (int r = 0; r < 4; ++r) {
        float v = fmaxf(fmaxf(sc[0][r], sc[1][r]), fmaxf(sc[2][r], sc[3][r]));
        v = fmaxf(v, __shfl_xor(v, 1));
        v = fmaxf(v, __shfl_xor(v, 2));
        v = fmaxf(v, __shfl_xor(v, 4));
        v = fmaxf(v, __shfl_xor(v, 8));
        const float mn = fmaxf(mrun[r], v);
        const float sf = __builtin_amdgcn_exp2f(mrun[r] - mn);
        mrun[r] = mn;
        float rs = 0.f;
#pragma unroll
        for (int n = 0; n < 4; ++n) {
          const float pv = __builtin_amdgcn_exp2f(sc[n][r] - mn);
          sc[n][r] = pv;
          rs += pv;
        }
        rs += __shfl_xor(rs, 1);
        rs += __shfl_xor(rs, 2);
        rs += __shfl_xor(rs, 4);
        rs += __shfl_xor(rs, 8);
        lrun[r] = lrun[r] * sf + rs;
#pragma unroll
        for (int nh = 0; nh < 8; ++nh) o[nh][r] *= sf;
      }
      // P (C-layout rows) -> per-wave LDS, padded stride 72
#pragma unroll
      for (int n = 0; n < 4; ++n)
#pragma unroll
        for (int r = 0; r < 4; ++r)
          lPw[(lg * 4 + r) * 72 + n * 16 + lr] = f2bf(sc[n][r]);

      // O += P V
#pragma unroll
      for (int kc2 = 0; kc2 < 2; ++kc2) {
        bf16x8 pa = *(const bf16x8*)&lPw[lr * 72 + kc2 * 32 + lg * 8];
#pragma unroll
        for (int nh = 0; nh < 8; ++nh) {
          const int row = nh * 16 + lr;
          const int us = (kc2 * 4 + lg) ^ (row & 7);
          bf16x8 bv = *(const bf16x8*)&lV[row * 64 + us * 8];
          o[nh] = __builtin_amdgcn_mfma_f32_16x16x32_bf16(pa, bv, o[nh], 0, 0, 0);
        }
      }
    }

#pragma unroll
    for (int nh = 0; nh < 8; ++nh)
#pragma unroll
      for (int r = 0; r < 4; ++r) {
        const float val = o[nh][r] / lrun[r];
        ao[(size_t)(q0 + lg * 4 + r) * EQ + h * HDIM + nh * 16 + lr] = f2bf(val);
      }
  }
}

// ---------------------------------------------------------------- launch
extern "C" void kernel_launch(void* const* d_in, const int* in_sizes, int n_in,
                              void* d_out, int out_size, void* d_ws, size_t ws_size,
                              hipStream_t stream) {
  (void)in_sizes; (void)n_in; (void)out_size; (void)ws_size;
  const float* x    = (const float*)d_in[0];
  const float* wq   = (const float*)d_in[1];
  const float* wk   = (const float*)d_in[2];
  const float* wv   = (const float*)d_in[3];
  const float* wo   = (const float*)d_in[4];
  const float* cosb = (const float*)d_in[7];
  const float* sinb = (const float*)d_in[8];
  const int*   sidx = (const int*)d_in[10];
  float* out = (float*)d_out;

  u16* ws  = (u16*)d_ws;
  u16* xb  = ws;                                  // 2048*4096
  u16* wqb = xb  + (size_t)S_LEN * DM;            // 4096*4096
  u16* wkb = wqb + (size_t)EQ * DM;               // 1024*4096
  u16* wvb = wkb + (size_t)EKV * DM;              // 1024*4096
  u16* wob = wvb + (size_t)EKV * DM;              // 4096*4096
  u16* qb  = wob + (size_t)DM * EQ;               // 2048*4096
  u16* kb  = qb  + (size_t)S_LEN * EQ;            // 2048*1024
  u16* vb  = kb  + (size_t)S_LEN * EKV;           // 2048*1024
  u16* vtb = vb  + (size_t)S_LEN * EKV;           // 1024*2048
  u16* aob = vtb + (size_t)S_LEN * EKV;           // 2048*4096

  cast_all<<<2048, 256, 0, stream>>>(x, wq, wk, wv, wo, xb, wqb, wkb, wvb, wob);
  gemm_nt<true><<<dim3(EQ / 128, S_LEN / 128), 256, 0, stream>>>(xb, wqb, qb, S_LEN, EQ, DM);
  gemm_nt<true><<<dim3(EKV / 128, S_LEN / 128), 256, 0, stream>>>(xb, wkb, kb, S_LEN, EKV, DM);
  gemm_nt<true><<<dim3(EKV / 128, S_LEN / 128), 256, 0, stream>>>(xb, wvb, vb, S_LEN, EKV, DM);
  rope_all<<<5120, 256, 0, stream>>>(qb, kb, cosb, sinb, sidx);
  transpose_v<<<dim3(EKV / 32, S_LEN / 32), dim3(32, 8), 0, stream>>>(vb, vtb);
  attn_fwd<<<dim3(16, NH), 256, 0, stream>>>(qb, kb, vtb, aob);
  gemm_nt<false><<<dim3(DM / 128, S_LEN / 128), 256, 0, stream>>>(aob, wob, out, S_LEN, DM, EQ);
}

// Round 4
// 365.980 us; speedup vs baseline: 1.4311x; 1.3092x over previous
//
#include <hip/hip_runtime.h>
#include <cstdint>
#include <cstddef>

#define S_LEN 2048
#define DM    4096
#define NH    32
#define NKV   8
#define HDIM  128
#define EQ    4096   // NH*HDIM
#define EKV   1024   // NKV*HDIM
#define SCALE 0.08838834764831845f
#define SC_LOG2E 0.1275325477889277f   // SCALE * log2(e)

typedef unsigned short u16;
typedef short bf16x8 __attribute__((ext_vector_type(8)));
typedef float f32x4  __attribute__((ext_vector_type(4)));

__device__ __forceinline__ u16 f2bf(float f) {
  union { float f; unsigned u; } v; v.f = f;
  unsigned r = v.u + 0x7FFFu + ((v.u >> 16) & 1u);
  return (u16)(r >> 16);
}
__device__ __forceinline__ float bf2f(u16 b) {
  union { unsigned u; float f; } v; v.u = ((unsigned)b) << 16;
  return v.f;
}
__device__ __forceinline__ void glds16(const void* g, void* l) {
  __builtin_amdgcn_global_load_lds((const __attribute__((address_space(1))) void*)g,
                                   (__attribute__((address_space(3))) void*)l, 16, 0, 0);
}

// ---------------------------------------------------------------- cast fp32->bf16
__global__ void cast_all(const float* __restrict__ x, const float* __restrict__ wq,
                         const float* __restrict__ wk, const float* __restrict__ wv,
                         const float* __restrict__ wo,
                         u16* __restrict__ xb, u16* __restrict__ wqb,
                         u16* __restrict__ wkb, u16* __restrict__ wvb,
                         u16* __restrict__ wob) {
  const size_t stride = (size_t)gridDim.x * blockDim.x;
  for (size_t u = (size_t)blockIdx.x * blockDim.x + threadIdx.x; u < 12582912u; u += stride) {
    const float* in; u16* outp; size_t i;
    if (u < 2097152u)      { in = x;  outp = xb;  i = u; }
    else if (u < 6291456u) { in = wq; outp = wqb; i = u - 2097152u; }
    else if (u < 7340032u) { in = wk; outp = wkb; i = u - 6291456u; }
    else if (u < 8388608u) { in = wv; outp = wvb; i = u - 7340032u; }
    else                   { in = wo; outp = wob; i = u - 8388608u; }
    float4 f = ((const float4*)in)[i];
    ushort4 b;
    b.x = f2bf(f.x); b.y = f2bf(f.y); b.z = f2bf(f.z); b.w = f2bf(f.w);
    ((ushort4*)outp)[i] = b;
  }
}

// ---------------------------------------------------------------- 8-phase 256x256 GEMM
// C = A * B^T, A[M,K], B[N,K] bf16 row-major. BM=BN=256, BK=64, 8 waves (2x4),
// per-wave output 128x64. LDS 128KB: A-ring 4 half-slots (128x64 each) +
// B-ring 4. Stage roles per K-tile t: ph0 B_lo(t+1), ph1 B_hi(t+1),
// ph2 A_lo(t+2), ph3 A_hi(t+2). Quadrants (mh,nh): ph0 (0,0), ph1 (1,0),
// ph2 (0,1), ph3 (1,1); both A subtiles kept in regs (last A read = ph1 <
// A overwrite at ph2; last B read = ph2 < B overwrite at next ph0).
// One vmcnt(4) per K-tile at ph3: every half-tile is staged >=3 phases before
// first read, with the producer-side waitcnt barrier-separated from consumers.
// 16B-unit XOR swizzle u^=(row&7): pre-swizzled global source (linear glds
// dest) + swizzled ds_read address (rule 21).
__device__ __forceinline__ void stage_half(const u16* __restrict__ g, int ldg, int k0,
                                           u16* ldsp, int t) {
  const int wb = t & ~63;
#pragma unroll
  for (int j = 0; j < 2; ++j) {
    const int U = j * 512 + t;
    const int row = U >> 3, u = U & 7;
    const int uu = u ^ (row & 7);
    glds16(g + (size_t)row * ldg + k0 + uu * 8, ldsp + (size_t)(j * 512 + wb) * 8);
  }
}

#define LOADA(MH) \
  { _Pragma("unroll") for (int m_ = 0; m_ < 4; ++m_) { \
      _Pragma("unroll") for (int kk_ = 0; kk_ < 2; ++kk_) { \
        afr[MH][m_][kk_] = *(const bf16x8*)&lds[aRd + arow + ((MH)*64 + m_*16)*64 + axo[kk_]]; } } }

#define LOADB(NH) \
  { _Pragma("unroll") for (int n_ = 0; n_ < 2; ++n_) { \
      _Pragma("unroll") for (int kk_ = 0; kk_ < 2; ++kk_) { \
        bfr[n_][kk_] = *(const bf16x8*)&lds[bRd + brow + ((NH)*32 + n_*16)*64 + axo[kk_]]; } } }

#define MFMA16(MH, NH) \
  { _Pragma("unroll") for (int m_ = 0; m_ < 4; ++m_) \
    _Pragma("unroll") for (int n_ = 0; n_ < 2; ++n_) \
    _Pragma("unroll") for (int kk_ = 0; kk_ < 2; ++kk_) \
      acc[(MH)*4+m_][(NH)*2+n_] = __builtin_amdgcn_mfma_f32_16x16x32_bf16( \
        afr[MH][m_][kk_], bfr[n_][kk_], acc[(MH)*4+m_][(NH)*2+n_], 0, 0, 0); }

#define GBAR() __builtin_amdgcn_s_barrier()
#define WLG()  { asm volatile("s_waitcnt lgkmcnt(0)" ::: "memory"); __builtin_amdgcn_sched_barrier(0); }
#define WVM4() { asm volatile("s_waitcnt vmcnt(4)" ::: "memory"); __builtin_amdgcn_sched_barrier(0); }

template<bool QKV3>
__global__ __launch_bounds__(512, 2)
void gemm8(const u16* __restrict__ A, const u16* __restrict__ B,
           void* __restrict__ Cq, u16* __restrict__ Ck, u16* __restrict__ Cv,
           int K) {
  __shared__ u16 lds[65536];   // A slots @ u16 {0,8192,16384,24576}; B @ 32768+
  const int t = threadIdx.x;
  const int l = t & 63, lr = l & 15, lg = l >> 4;
  const int wid = t >> 6, wm = wid >> 2, wn = wid & 3;
  const int m0 = blockIdx.y * 256, n0 = blockIdx.x * 256;
  const int KT = K >> 6;

  const int arow = lr * 64;
  const int brow = ((wn & 1) * 64 + lr) * 64;
  int axo[2];
  axo[0] = (lg ^ (lr & 7)) * 8;
  axo[1] = ((4 + lg) ^ (lr & 7)) * 8;

  const u16* Alo = A + (size_t)m0 * K;
  const u16* Ahi = A + (size_t)(m0 + 128) * K;
  const u16* Blo = B + (size_t)n0 * K;
  const u16* Bhi = B + (size_t)(n0 + 128) * K;

  f32x4 acc[8][4] = {};
  bf16x8 afr[2][4][2], bfr[2][2];

  // prologue: B(0) lo/hi, A(0) lo/hi, A(1) lo/hi; drain; barrier.
  stage_half(Blo, K, 0, &lds[32768], t);
  stage_half(Bhi, K, 0, &lds[32768 + 8192], t);
  stage_half(Alo, K, 0, &lds[0], t);
  stage_half(Ahi, K, 0, &lds[8192], t);
  stage_half(Alo, K, 64, &lds[16384], t);
  stage_half(Ahi, K, 64, &lds[24576], t);
  asm volatile("s_waitcnt vmcnt(0)" ::: "memory");
  GBAR();

#pragma unroll 1
  for (int tau = 0; tau < KT; ++tau) {
    const int P = tau & 1;
    const int aRd = (P * 2 + wm) * 8192;
    const int bRd = 32768 + (P * 2 + (wn >> 1)) * 8192;
    const int bSt = 32768 + (1 - P) * 16384;
    const int aSt = P * 16384;
    const int kB = (tau + 1 < KT ? tau + 1 : KT - 1) * 64;
    const int kA = (tau + 2 < KT ? tau + 2 : KT - 1) * 64;

    // ---- phase 0: ds A(mh0)+B(nh0); stage B_lo(t+1); mfma (0,0)
    LOADA(0) LOADB(0)
    stage_half(Blo, K, kB, &lds[bSt], t);
    GBAR(); WLG();
    __builtin_amdgcn_s_setprio(1); MFMA16(0, 0); __builtin_amdgcn_s_setprio(0);
    GBAR();
    // ---- phase 1: ds A(mh1); stage B_hi(t+1); mfma (1,0)
    LOADA(1)
    stage_half(Bhi, K, kB, &lds[bSt + 8192], t);
    GBAR(); WLG();
    __builtin_amdgcn_s_setprio(1); MFMA16(1, 0); __builtin_amdgcn_s_setprio(0);
    GBAR();
    // ---- phase 2: ds B(nh1); stage A_lo(t+2); mfma (0,1)
    LOADB(1)
    stage_half(Alo, K, kA, &lds[aSt], t);
    GBAR(); WLG();
    __builtin_amdgcn_s_setprio(1); MFMA16(0, 1); __builtin_amdgcn_s_setprio(0);
    GBAR();
    // ---- phase 3: stage A_hi(t+2); vmcnt(4); mfma (1,1)
    stage_half(Ahi, K, kA, &lds[aSt + 8192], t);
    GBAR(); WVM4();
    __builtin_amdgcn_s_setprio(1); MFMA16(1, 1); __builtin_amdgcn_s_setprio(0);
    GBAR();
  }

  // epilogue
#pragma unroll
  for (int am = 0; am < 8; ++am) {
    const int row = m0 + wm * 128 + (am >> 2) * 64 + (am & 3) * 16 + lg * 4;
#pragma unroll
    for (int an = 0; an < 4; ++an) {
      const int col = wn * 64 + (an >> 1) * 32 + (an & 1) * 16 + lr;
#pragma unroll
      for (int r = 0; r < 4; ++r) {
        if constexpr (QKV3) {
          u16* cp; int ldc, cc;
          if (n0 < 4096)      { cp = (u16*)Cq; ldc = 4096; cc = n0 + col; }
          else if (n0 < 5120) { cp = Ck;       ldc = 1024; cc = n0 - 4096 + col; }
          else                { cp = Cv;       ldc = 1024; cc = n0 - 5120 + col; }
          cp[(size_t)(row + r) * ldc + cc] = f2bf(acc[am][an][r]);
        } else {
          ((float*)Cq)[(size_t)(row + r) * 4096 + n0 + col] = acc[am][an][r];
        }
      }
    }
  }
}

// ---------------------------------------------------------------- RoPE (q then k)
__global__ void rope_all(u16* __restrict__ qd, u16* __restrict__ kd,
                         const float* __restrict__ cosb, const float* __restrict__ sinb,
                         const int* __restrict__ sidx) {
  const int u = blockIdx.x * blockDim.x + threadIdx.x;
  u16* base; int s, b;
  if (u < 1048576) {
    base = qd + (size_t)u * 8;
    s = u >> 9;
    b = u & 15;
  } else if (u < 1310720) {
    const int u2 = u - 1048576;
    base = kd + (size_t)u2 * 8;
    s = u2 >> 7;
    b = u2 & 15;
  } else return;
  const int pos = sidx[s];
  const float4 c  = *(const float4*)&cosb[pos * 64 + b * 4];
  const float4 sn = *(const float4*)&sinb[pos * 64 + b * 4];
  uint4 raw = *(uint4*)base;
  u16* pe = (u16*)&raw;
  const float cc[4] = {c.x, c.y, c.z, c.w};
  const float ss[4] = {sn.x, sn.y, sn.z, sn.w};
#pragma unroll
  for (int j = 0; j < 4; ++j) {
    const float xr = bf2f(pe[2 * j]), xi = bf2f(pe[2 * j + 1]);
    pe[2 * j]     = f2bf(xr * cc[j] - xi * ss[j]);
    pe[2 * j + 1] = f2bf(xr * ss[j] + xi * cc[j]);
  }
  *(uint4*)base = raw;
}

// ---------------------------------------------------------------- V transpose
__global__ void transpose_v(const u16* __restrict__ v, u16* __restrict__ vt) {
  __shared__ u16 tile[32][33];
  const int tx = threadIdx.x, ty = threadIdx.y;
  const int c0 = blockIdx.x * 32, s0 = blockIdx.y * 32;
#pragma unroll
  for (int j = 0; j < 32; j += 8)
    tile[ty + j][tx] = v[(size_t)(s0 + ty + j) * EKV + c0 + tx];
  __syncthreads();
#pragma unroll
  for (int j = 0; j < 32; j += 8)
    vt[(size_t)(c0 + ty + j) * S_LEN + s0 + tx] = tile[tx][ty + j];
}

// ---------------------------------------------------------------- flash attention
// Causal-paired blocks (p, 31-p): 33 KV-tiles per block, perfectly balanced.
__global__ __launch_bounds__(256, 2)
void attn_fwd(const u16* __restrict__ q, const u16* __restrict__ k,
              const u16* __restrict__ vt, u16* __restrict__ ao) {
  __shared__ u16 lK[64 * 128];
  __shared__ u16 lV[128 * 64];
  __shared__ u16 lP[4 * 16 * 72];
  const int t = threadIdx.x, w = t >> 6, l = t & 63;
  const int lr = l & 15, lg = l >> 4;
  const int wb = t & ~63;
  const int p = blockIdx.x, h = blockIdx.y;
  const int kvh = h >> 2;
  u16* lPw = &lP[w * (16 * 72)];

#pragma unroll 1
  for (int ph = 0; ph < 2; ++ph) {
    const int qt = ph ? (31 - p) : p;
    const int q0 = qt * 64 + w * 16;
    const int nt = qt + 1;

    bf16x8 qa[4];
#pragma unroll
    for (int kc = 0; kc < 4; ++kc)
      qa[kc] = *(const bf16x8*)&q[(size_t)(q0 + lr) * EQ + h * HDIM + kc * 32 + lg * 8];

    f32x4 o[8] = {};
    float mrun[4], lrun[4];
#pragma unroll
    for (int r = 0; r < 4; ++r) { mrun[r] = -1e30f; lrun[r] = 0.f; }

    for (int tk = 0; tk < nt; ++tk) {
      const int kv0 = tk * 64;
      __syncthreads();
#pragma unroll
      for (int hh = 0; hh < 4; ++hh) {
        const int f = hh * 256 + t;
        { const int row = f >> 4, u = f & 15, us = u ^ (row & 7);
          glds16(&k[(size_t)(kv0 + row) * EKV + kvh * HDIM + us * 8], &lK[(hh * 256 + wb) * 8]); }
        { const int row = f >> 3, u = f & 7, us = u ^ (row & 7);
          glds16(&vt[(size_t)(kvh * HDIM + row) * S_LEN + kv0 + us * 8], &lV[(hh * 256 + wb) * 8]); }
      }
      __syncthreads();

      f32x4 sc[4] = {};
#pragma unroll
      for (int n = 0; n < 4; ++n) {
#pragma unroll
        for (int kc = 0; kc < 4; ++kc) {
          const int row = n * 16 + lr;
          const int us = (kc * 4 + lg) ^ (row & 7);
          bf16x8 bk = *(const bf16x8*)&lK[row * 128 + us * 8];
          sc[n] = __builtin_amdgcn_mfma_f32_16x16x32_bf16(qa[kc], bk, sc[n], 0, 0, 0);
        }
      }

#pragma unroll
      for (int n = 0; n < 4; ++n) {
        const int kvc = kv0 + n * 16 + lr;
#pragma unroll
        for (int r = 0; r < 4; ++r) {
          const int qr = q0 + lg * 4 + r;
          const float v = sc[n][r] * SC_LOG2E;
          sc[n][r] = (kvc > qr) ? -1e30f : v;
        }
      }
#pragma unroll
      for (int r = 0; r < 4; ++r) {
        float v = fmaxf(fmaxf(sc[0][r], sc[1][r]), fmaxf(sc[2][r], sc[3][r]));
        v = fmaxf(v, __shfl_xor(v, 1));
        v = fmaxf(v, __shfl_xor(v, 2));
        v = fmaxf(v, __shfl_xor(v, 4));
        v = fmaxf(v, __shfl_xor(v, 8));
        const float mn = fmaxf(mrun[r], v);
        const float sf = __builtin_amdgcn_exp2f(mrun[r] - mn);
        mrun[r] = mn;
        float rs = 0.f;
#pragma unroll
        for (int n = 0; n < 4; ++n) {
          const float pv = __builtin_amdgcn_exp2f(sc[n][r] - mn);
          sc[n][r] = pv;
          rs += pv;
        }
        rs += __shfl_xor(rs, 1);
        rs += __shfl_xor(rs, 2);
        rs += __shfl_xor(rs, 4);
        rs += __shfl_xor(rs, 8);
        lrun[r] = lrun[r] * sf + rs;
#pragma unroll
        for (int nh = 0; nh < 8; ++nh) o[nh][r] *= sf;
      }
#pragma unroll
      for (int n = 0; n < 4; ++n)
#pragma unroll
        for (int r = 0; r < 4; ++r)
          lPw[(lg * 4 + r) * 72 + n * 16 + lr] = f2bf(sc[n][r]);

#pragma unroll
      for (int kc2 = 0; kc2 < 2; ++kc2) {
        bf16x8 pa = *(const bf16x8*)&lPw[lr * 72 + kc2 * 32 + lg * 8];
#pragma unroll
        for (int nh = 0; nh < 8; ++nh) {
          const int row = nh * 16 + lr;
          const int us = (kc2 * 4 + lg) ^ (row & 7);
          bf16x8 bv = *(const bf16x8*)&lV[row * 64 + us * 8];
          o[nh] = __builtin_amdgcn_mfma_f32_16x16x32_bf16(pa, bv, o[nh], 0, 0, 0);
        }
      }
    }

#pragma unroll
    for (int nh = 0; nh < 8; ++nh)
#pragma unroll
      for (int r = 0; r < 4; ++r) {
        const float val = o[nh][r] / lrun[r];
        ao[(size_t)(q0 + lg * 4 + r) * EQ + h * HDIM + nh * 16 + lr] = f2bf(val);
      }
  }
}

// ---------------------------------------------------------------- launch
extern "C" void kernel_launch(void* const* d_in, const int* in_sizes, int n_in,
                              void* d_out, int out_size, void* d_ws, size_t ws_size,
                              hipStream_t stream) {
  (void)in_sizes; (void)n_in; (void)out_size; (void)ws_size;
  const float* x    = (const float*)d_in[0];
  const float* wq   = (const float*)d_in[1];
  const float* wk   = (const float*)d_in[2];
  const float* wv   = (const float*)d_in[3];
  const float* wo   = (const float*)d_in[4];
  const float* cosb = (const float*)d_in[7];
  const float* sinb = (const float*)d_in[8];
  const int*   sidx = (const int*)d_in[10];
  float* out = (float*)d_out;

  // workspace layout; wqb/wkb/wvb are contiguous so B_qkv = [wq;wk;wv]
  u16* ws  = (u16*)d_ws;
  u16* xb  = ws;                                  // 2048*4096
  u16* wqb = xb  + (size_t)S_LEN * DM;            // 4096*4096
  u16* wkb = wqb + (size_t)EQ * DM;               // 1024*4096
  u16* wvb = wkb + (size_t)EKV * DM;              // 1024*4096
  u16* wob = wvb + (size_t)EKV * DM;              // 4096*4096
  u16* qb  = wob + (size_t)DM * EQ;               // 2048*4096
  u16* kb  = qb  + (size_t)S_LEN * EQ;            // 2048*1024
  u16* vb  = kb  + (size_t)S_LEN * EKV;           // 2048*1024
  u16* vtb = vb  + (size_t)S_LEN * EKV;           // 1024*2048
  u16* aob = vtb + (size_t)S_LEN * EKV;           // 2048*4096

  cast_all<<<2048, 256, 0, stream>>>(x, wq, wk, wv, wo, xb, wqb, wkb, wvb, wob);
  // fused QKV projection: B = [wq;wk;wv] (6144 x 4096), routed epilogue
  gemm8<true><<<dim3(24, 8), 512, 0, stream>>>(xb, wqb, qb, kb, vb, DM);
  rope_all<<<5120, 256, 0, stream>>>(qb, kb, cosb, sinb, sidx);
  transpose_v<<<dim3(EKV / 32, S_LEN / 32), dim3(32, 8), 0, stream>>>(vb, vtb);
  attn_fwd<<<dim3(16, NH), 256, 0, stream>>>(qb, kb, vtb, aob);
  gemm8<false><<<dim3(16, 8), 512, 0, stream>>>(aob, wob, out, nullptr, nullptr, EQ);
}

// Round 5
// 326.034 us; speedup vs baseline: 1.6064x; 1.1225x over previous
//
#include <hip/hip_runtime.h>
#include <cstdint>
#include <cstddef>

#define S_LEN 2048
#define DM    4096
#define NH    32
#define NKV   8
#define HDIM  128
#define EQ    4096   // NH*HDIM
#define EKV   1024   // NKV*HDIM
#define SCALE 0.08838834764831845f
#define SC_LOG2E 0.1275325477889277f   // SCALE * log2(e)

typedef unsigned short u16;
typedef short bf16x8 __attribute__((ext_vector_type(8)));
typedef float f32x4  __attribute__((ext_vector_type(4)));

__device__ __forceinline__ u16 f2bf(float f) {
  union { float f; unsigned u; } v; v.f = f;
  unsigned r = v.u + 0x7FFFu + ((v.u >> 16) & 1u);
  return (u16)(r >> 16);
}
__device__ __forceinline__ float bf2f(u16 b) {
  union { unsigned u; float f; } v; v.u = ((unsigned)b) << 16;
  return v.f;
}
__device__ __forceinline__ void glds16(const void* g, void* l) {
  __builtin_amdgcn_global_load_lds((const __attribute__((address_space(1))) void*)g,
                                   (__attribute__((address_space(3))) void*)l, 16, 0, 0);
}

// ---------------------------------------------------------------- cast fp32->bf16
__global__ void cast_all(const float* __restrict__ x, const float* __restrict__ wq,
                         const float* __restrict__ wk, const float* __restrict__ wv,
                         const float* __restrict__ wo,
                         u16* __restrict__ xb, u16* __restrict__ wqb,
                         u16* __restrict__ wkb, u16* __restrict__ wvb,
                         u16* __restrict__ wob) {
  const size_t stride = (size_t)gridDim.x * blockDim.x;
  for (size_t u = (size_t)blockIdx.x * blockDim.x + threadIdx.x; u < 12582912u; u += stride) {
    const float* in; u16* outp; size_t i;
    if (u < 2097152u)      { in = x;  outp = xb;  i = u; }
    else if (u < 6291456u) { in = wq; outp = wqb; i = u - 2097152u; }
    else if (u < 7340032u) { in = wk; outp = wkb; i = u - 6291456u; }
    else if (u < 8388608u) { in = wv; outp = wvb; i = u - 7340032u; }
    else                   { in = wo; outp = wob; i = u - 8388608u; }
    float4 f = ((const float4*)in)[i];
    ushort4 b;
    b.x = f2bf(f.x); b.y = f2bf(f.y); b.z = f2bf(f.z); b.w = f2bf(f.w);
    ((ushort4*)outp)[i] = b;
  }
}

// ---------------------------------------------------------------- 8-phase GEMM, BM=256, BN=64*NF
// C = A * B^T. 8 waves (2 row x 4 col), wave-tile 128 x 16*NF. BK=64.
// LDS: A ring 4 half-slots (128x64 = 16KB each) + B ring 4 half-slots
// (32*NF x 64). Stage roles: ph0 B_lo(t+1), ph1 B_hi(t+1), ph2 A_lo(t+2),
// ph3 A_hi(t+2). MFMA quadrants split by (mh, kk): ph0 (0,k0), ph1 (1,k0),
// ph2 (0,k1), ph3 (1,k1). ALL A/B ds_reads confined to ph0/ph1 so the A-slot
// overwrite at ph2/ph3 is barrier-separated from every reader.
// One vmcnt(4) per K-tile at ph3 = "4 newest (A) loads in flight"; holds for
// both wave groups even when the B stage is a 1.5-pass (NF=3) partial issue.
// 16B-unit XOR swizzle u^=(row&7): pre-swizzled global source (linear glds
// dest) + swizzled ds_read address. Grids chosen so grid == 256 == 1 block/CU.
template<int UN>
__device__ __forceinline__ void stage_units(const u16* __restrict__ g, int ldg, int k0,
                                            u16* ldsp, int t) {
  const int wb = t & ~63;
#pragma unroll
  for (int j = 0; j * 512 < UN; ++j) {
    const int U = j * 512 + t;
    if ((UN % 512 == 0) || (U < UN)) {
      const int row = U >> 3, u = U & 7;
      const int uu = u ^ (row & 7);
      glds16(g + (size_t)row * ldg + k0 + uu * 8, ldsp + (size_t)(j * 512 + wb) * 8);
    }
  }
}

#define LOADA2(MH) \
  { _Pragma("unroll") for (int m_ = 0; m_ < 4; ++m_) { \
      _Pragma("unroll") for (int kk_ = 0; kk_ < 2; ++kk_) { \
        afr[MH][m_][kk_] = *(const bf16x8*)&lds[aRd + arow + ((MH)*64 + m_*16)*64 + axo[kk_]]; } } }

#define LOADBK(KK) \
  { _Pragma("unroll") for (int n_ = 0; n_ < NF; ++n_) { \
        bfr[KK][n_] = *(const bf16x8*)&lds[bRd + ((wn & 1)*16*NF + n_*16 + lr)*64 + axo[KK]]; } }

#define MFMAC(MH, KK) \
  { _Pragma("unroll") for (int m_ = 0; m_ < 4; ++m_) \
    _Pragma("unroll") for (int n_ = 0; n_ < NF; ++n_) \
      acc[(MH)*4+m_][n_] = __builtin_amdgcn_mfma_f32_16x16x32_bf16( \
        afr[MH][m_][KK], bfr[KK][n_], acc[(MH)*4+m_][n_], 0, 0, 0); }

#define GBAR() __builtin_amdgcn_s_barrier()
#define WLG()  { asm volatile("s_waitcnt lgkmcnt(0)" ::: "memory"); __builtin_amdgcn_sched_barrier(0); }
#define WVM4() { asm volatile("s_waitcnt vmcnt(4)" ::: "memory"); __builtin_amdgcn_sched_barrier(0); }

template<int NF, bool QKV3>
__global__ __launch_bounds__(512, 2)
void gemm8(const u16* __restrict__ A, const u16* __restrict__ B,
           void* __restrict__ Cq, u16* __restrict__ Ck, u16* __restrict__ Cv,
           int K) {
  constexpr int BSLOT = 2048 * NF;          // u16 per B half-slot (32*NF x 64)
  constexpr int BUN   = 256 * NF;           // 16B units per B half-slot
  __shared__ u16 lds[32768 + 4 * BSLOT];    // A slots u16 {0,8192,16384,24576}; B at 32768+
  const int t = threadIdx.x;
  const int l = t & 63, lr = l & 15, lg = l >> 4;
  const int wid = t >> 6, wm = wid >> 2, wn = wid & 3;
  const int m0 = blockIdx.y * 256, n0 = blockIdx.x * (64 * NF);
  const int KT = K >> 6;

  const int arow = lr * 64;
  int axo[2];
  axo[0] = (lg ^ (lr & 7)) * 8;
  axo[1] = ((4 + lg) ^ (lr & 7)) * 8;

  const u16* Alo = A + (size_t)m0 * K;
  const u16* Ahi = A + (size_t)(m0 + 128) * K;
  const u16* Blo = B + (size_t)n0 * K;
  const u16* Bhi = B + (size_t)(n0 + 32 * NF) * K;

  f32x4 acc[8][NF] = {};
  bf16x8 afr[2][4][2], bfr[2][NF];

  // prologue: B(0) lo/hi -> B slots 0,1; A(0) -> A slots 0,1; A(1) -> 2,3.
  stage_units<BUN>(Blo, K, 0, &lds[32768], t);
  stage_units<BUN>(Bhi, K, 0, &lds[32768 + BSLOT], t);
  stage_units<1024>(Alo, K, 0, &lds[0], t);
  stage_units<1024>(Ahi, K, 0, &lds[8192], t);
  stage_units<1024>(Alo, K, 64, &lds[16384], t);
  stage_units<1024>(Ahi, K, 64, &lds[24576], t);
  asm volatile("s_waitcnt vmcnt(0)" ::: "memory");
  GBAR();

#pragma unroll 1
  for (int tau = 0; tau < KT; ++tau) {
    const int P = tau & 1;
    const int aRd = (P * 2 + wm) * 8192;
    const int bRd = 32768 + (P * 2 + (wn >> 1)) * BSLOT;
    const int bSt = 32768 + (1 - P) * 2 * BSLOT;
    const int aSt = P * 16384;
    const int kB = (tau + 1 < KT ? tau + 1 : KT - 1) * 64;
    const int kA = (tau + 2 < KT ? tau + 2 : KT - 1) * 64;

    // ---- phase 0: ds A(mh0, kk0+kk1) + B(kk0); stage B_lo(t+1); mfma (0,k0)
    LOADA2(0) LOADBK(0)
    stage_units<BUN>(Blo, K, kB, &lds[bSt], t);
    GBAR(); WLG();
    __builtin_amdgcn_s_setprio(1); MFMAC(0, 0); __builtin_amdgcn_s_setprio(0);
    GBAR();
    // ---- phase 1: ds A(mh1, kk0+kk1) + B(kk1); stage B_hi(t+1); mfma (1,k0)
    LOADA2(1) LOADBK(1)
    stage_units<BUN>(Bhi, K, kB, &lds[bSt + BSLOT], t);
    GBAR(); WLG();
    __builtin_amdgcn_s_setprio(1); MFMAC(1, 0); __builtin_amdgcn_s_setprio(0);
    GBAR();
    // ---- phase 2: stage A_lo(t+2); mfma (0,k1)
    stage_units<1024>(Alo, K, kA, &lds[aSt], t);
    GBAR();
    __builtin_amdgcn_s_setprio(1); MFMAC(0, 1); __builtin_amdgcn_s_setprio(0);
    GBAR();
    // ---- phase 3: stage A_hi(t+2); vmcnt(4); mfma (1,k1)
    stage_units<1024>(Ahi, K, kA, &lds[aSt + 8192], t);
    GBAR(); WVM4();
    __builtin_amdgcn_s_setprio(1); MFMAC(1, 1); __builtin_amdgcn_s_setprio(0);
    GBAR();
  }

  // epilogue; fragments are 16-col aligned so QKV routing is per-fragment
#pragma unroll
  for (int am = 0; am < 8; ++am) {
    const int row = m0 + wm * 128 + (am >> 2) * 64 + (am & 3) * 16 + lg * 4;
#pragma unroll
    for (int an = 0; an < NF; ++an) {
      const int gc = n0 + wn * (16 * NF) + an * 16 + lr;
#pragma unroll
      for (int r = 0; r < 4; ++r) {
        if constexpr (QKV3) {
          if (gc < 4096)
            ((u16*)Cq)[(size_t)(row + r) * 4096 + gc] = f2bf(acc[am][an][r]);
          else if (gc < 5120)
            Ck[(size_t)(row + r) * 1024 + (gc - 4096)] = f2bf(acc[am][an][r]);
          else
            Cv[(size_t)(row + r) * 1024 + (gc - 5120)] = f2bf(acc[am][an][r]);
        } else {
          ((float*)Cq)[(size_t)(row + r) * 4096 + gc] = acc[am][an][r];
        }
      }
    }
  }
}

// ---------------------------------------------------------------- RoPE (q then k)
__global__ void rope_all(u16* __restrict__ qd, u16* __restrict__ kd,
                         const float* __restrict__ cosb, const float* __restrict__ sinb,
                         const int* __restrict__ sidx) {
  const int u = blockIdx.x * blockDim.x + threadIdx.x;
  u16* base; int s, b;
  if (u < 1048576) {
    base = qd + (size_t)u * 8;
    s = u >> 9;
    b = u & 15;
  } else if (u < 1310720) {
    const int u2 = u - 1048576;
    base = kd + (size_t)u2 * 8;
    s = u2 >> 7;
    b = u2 & 15;
  } else return;
  const int pos = sidx[s];
  const float4 c  = *(const float4*)&cosb[pos * 64 + b * 4];
  const float4 sn = *(const float4*)&sinb[pos * 64 + b * 4];
  uint4 raw = *(uint4*)base;
  u16* pe = (u16*)&raw;
  const float cc[4] = {c.x, c.y, c.z, c.w};
  const float ss[4] = {sn.x, sn.y, sn.z, sn.w};
#pragma unroll
  for (int j = 0; j < 4; ++j) {
    const float xr = bf2f(pe[2 * j]), xi = bf2f(pe[2 * j + 1]);
    pe[2 * j]     = f2bf(xr * cc[j] - xi * ss[j]);
    pe[2 * j + 1] = f2bf(xr * ss[j] + xi * cc[j]);
  }
  *(uint4*)base = raw;
}

// ---------------------------------------------------------------- V transpose
__global__ void transpose_v(const u16* __restrict__ v, u16* __restrict__ vt) {
  __shared__ u16 tile[32][33];
  const int tx = threadIdx.x, ty = threadIdx.y;
  const int c0 = blockIdx.x * 32, s0 = blockIdx.y * 32;
#pragma unroll
  for (int j = 0; j < 32; j += 8)
    tile[ty + j][tx] = v[(size_t)(s0 + ty + j) * EKV + c0 + tx];
  __syncthreads();
#pragma unroll
  for (int j = 0; j < 32; j += 8)
    vt[(size_t)(c0 + ty + j) * S_LEN + s0 + tx] = tile[tx][ty + j];
}

// ---------------------------------------------------------------- flash attention
// Causal-paired blocks (p, 31-p): 33 KV-tiles per block, perfectly balanced.
__global__ __launch_bounds__(256, 2)
void attn_fwd(const u16* __restrict__ q, const u16* __restrict__ k,
              const u16* __restrict__ vt, u16* __restrict__ ao) {
  __shared__ u16 lK[64 * 128];
  __shared__ u16 lV[128 * 64];
  __shared__ u16 lP[4 * 16 * 72];
  const int t = threadIdx.x, w = t >> 6, l = t & 63;
  const int lr = l & 15, lg = l >> 4;
  const int wb = t & ~63;
  const int p = blockIdx.x, h = blockIdx.y;
  const int kvh = h >> 2;
  u16* lPw = &lP[w * (16 * 72)];

#pragma unroll 1
  for (int ph = 0; ph < 2; ++ph) {
    const int qt = ph ? (31 - p) : p;
    const int q0 = qt * 64 + w * 16;
    const int nt = qt + 1;

    bf16x8 qa[4];
#pragma unroll
    for (int kc = 0; kc < 4; ++kc)
      qa[kc] = *(const bf16x8*)&q[(size_t)(q0 + lr) * EQ + h * HDIM + kc * 32 + lg * 8];

    f32x4 o[8] = {};
    float mrun[4], lrun[4];
#pragma unroll
    for (int r = 0; r < 4; ++r) { mrun[r] = -1e30f; lrun[r] = 0.f; }

    for (int tk = 0; tk < nt; ++tk) {
      const int kv0 = tk * 64;
      __syncthreads();
#pragma unroll
      for (int hh = 0; hh < 4; ++hh) {
        const int f = hh * 256 + t;
        { const int row = f >> 4, u = f & 15, us = u ^ (row & 7);
          glds16(&k[(size_t)(kv0 + row) * EKV + kvh * HDIM + us * 8], &lK[(hh * 256 + wb) * 8]); }
        { const int row = f >> 3, u = f & 7, us = u ^ (row & 7);
          glds16(&vt[(size_t)(kvh * HDIM + row) * S_LEN + kv0 + us * 8], &lV[(hh * 256 + wb) * 8]); }
      }
      __syncthreads();

      f32x4 sc[4] = {};
#pragma unroll
      for (int n = 0; n < 4; ++n) {
#pragma unroll
        for (int kc = 0; kc < 4; ++kc) {
          const int row = n * 16 + lr;
          const int us = (kc * 4 + lg) ^ (row & 7);
          bf16x8 bk = *(const bf16x8*)&lK[row * 128 + us * 8];
          sc[n] = __builtin_amdgcn_mfma_f32_16x16x32_bf16(qa[kc], bk, sc[n], 0, 0, 0);
        }
      }

#pragma unroll
      for (int n = 0; n < 4; ++n) {
        const int kvc = kv0 + n * 16 + lr;
#pragma unroll
        for (int r = 0; r < 4; ++r) {
          const int qr = q0 + lg * 4 + r;
          const float v = sc[n][r] * SC_LOG2E;
          sc[n][r] = (kvc > qr) ? -1e30f : v;
        }
      }
#pragma unroll
      for (int r = 0; r < 4; ++r) {
        float v = fmaxf(fmaxf(sc[0][r], sc[1][r]), fmaxf(sc[2][r], sc[3][r]));
        v = fmaxf(v, __shfl_xor(v, 1));
        v = fmaxf(v, __shfl_xor(v, 2));
        v = fmaxf(v, __shfl_xor(v, 4));
        v = fmaxf(v, __shfl_xor(v, 8));
        const float mn = fmaxf(mrun[r], v);
        const float sf = __builtin_amdgcn_exp2f(mrun[r] - mn);
        mrun[r] = mn;
        float rs = 0.f;
#pragma unroll
        for (int n = 0; n < 4; ++n) {
          const float pv = __builtin_amdgcn_exp2f(sc[n][r] - mn);
          sc[n][r] = pv;
          rs += pv;
        }
        rs += __shfl_xor(rs, 1);
        rs += __shfl_xor(rs, 2);
        rs += __shfl_xor(rs, 4);
        rs += __shfl_xor(rs, 8);
        lrun[r] = lrun[r] * sf + rs;
#pragma unroll
        for (int nh = 0; nh < 8; ++nh) o[nh][r] *= sf;
      }
#pragma unroll
      for (int n = 0; n < 4; ++n)
#pragma unroll
        for (int r = 0; r < 4; ++r)
          lPw[(lg * 4 + r) * 72 + n * 16 + lr] = f2bf(sc[n][r]);

#pragma unroll
      for (int kc2 = 0; kc2 < 2; ++kc2) {
        bf16x8 pa = *(const bf16x8*)&lPw[lr * 72 + kc2 * 32 + lg * 8];
#pragma unroll
        for (int nh = 0; nh < 8; ++nh) {
          const int row = nh * 16 + lr;
          const int us = (kc2 * 4 + lg) ^ (row & 7);
          bf16x8 bv = *(const bf16x8*)&lV[row * 64 + us * 8];
          o[nh] = __builtin_amdgcn_mfma_f32_16x16x32_bf16(pa, bv, o[nh], 0, 0, 0);
        }
      }
    }

#pragma unroll
    for (int nh = 0; nh < 8; ++nh)
#pragma unroll
      for (int r = 0; r < 4; ++r) {
        const float val = o[nh][r] / lrun[r];
        ao[(size_t)(q0 + lg * 4 + r) * EQ + h * HDIM + nh * 16 + lr] = f2bf(val);
      }
  }
}

// ---------------------------------------------------------------- launch
extern "C" void kernel_launch(void* const* d_in, const int* in_sizes, int n_in,
                              void* d_out, int out_size, void* d_ws, size_t ws_size,
                              hipStream_t stream) {
  (void)in_sizes; (void)n_in; (void)out_size; (void)ws_size;
  const float* x    = (const float*)d_in[0];
  const float* wq   = (const float*)d_in[1];
  const float* wk   = (const float*)d_in[2];
  const float* wv   = (const float*)d_in[3];
  const float* wo   = (const float*)d_in[4];
  const float* cosb = (const float*)d_in[7];
  const float* sinb = (const float*)d_in[8];
  const int*   sidx = (const int*)d_in[10];
  float* out = (float*)d_out;

  // workspace layout; wqb/wkb/wvb are contiguous so B_qkv = [wq;wk;wv]
  u16* ws  = (u16*)d_ws;
  u16* xb  = ws;                                  // 2048*4096
  u16* wqb = xb  + (size_t)S_LEN * DM;            // 4096*4096
  u16* wkb = wqb + (size_t)EQ * DM;               // 1024*4096
  u16* wvb = wkb + (size_t)EKV * DM;              // 1024*4096
  u16* wob = wvb + (size_t)EKV * DM;              // 4096*4096
  u16* qb  = wob + (size_t)DM * EQ;               // 2048*4096
  u16* kb  = qb  + (size_t)S_LEN * EQ;            // 2048*1024
  u16* vb  = kb  + (size_t)S_LEN * EKV;           // 2048*1024
  u16* vtb = vb  + (size_t)S_LEN * EKV;           // 1024*2048
  u16* aob = vtb + (size_t)S_LEN * EKV;           // 2048*4096

  cast_all<<<2048, 256, 0, stream>>>(x, wq, wk, wv, wo, xb, wqb, wkb, wvb, wob);
  // fused QKV projection: B = [wq;wk;wv] (6144 x 4096), BN=192 -> 32x8 = 256 blocks
  gemm8<3, true><<<dim3(32, 8), 512, 0, stream>>>(xb, wqb, qb, kb, vb, DM);
  rope_all<<<5120, 256, 0, stream>>>(qb, kb, cosb, sinb, sidx);
  transpose_v<<<dim3(EKV / 32, S_LEN / 32), dim3(32, 8), 0, stream>>>(vb, vtb);
  attn_fwd<<<dim3(16, NH), 256, 0, stream>>>(qb, kb, vtb, aob);
  // O projection: BN=128 -> 32x8 = 256 blocks
  gemm8<2, false><<<dim3(32, 8), 512, 0, stream>>>(aob, wob, out, nullptr, nullptr, EQ);
}

// Round 6
// 322.650 us; speedup vs baseline: 1.6233x; 1.0105x over previous
//
#include <hip/hip_runtime.h>
#include <cstdint>
#include <cstddef>

#define S_LEN 2048
#define DM    4096
#define NH    32
#define NKV   8
#define HDIM  128
#define EQ    4096   // NH*HDIM
#define EKV   1024   // NKV*HDIM
#define SCALE 0.08838834764831845f
#define SC_LOG2E 0.1275325477889277f   // SCALE * log2(e)

typedef unsigned short u16;
typedef short bf16x8 __attribute__((ext_vector_type(8)));
typedef float f32x4  __attribute__((ext_vector_type(4)));

__device__ __forceinline__ u16 f2bf(float f) {
  union { float f; unsigned u; } v; v.f = f;
  unsigned r = v.u + 0x7FFFu + ((v.u >> 16) & 1u);
  return (u16)(r >> 16);
}
__device__ __forceinline__ float bf2f(u16 b) {
  union { unsigned u; float f; } v; v.u = ((unsigned)b) << 16;
  return v.f;
}
__device__ __forceinline__ void glds16(const void* g, void* l) {
  __builtin_amdgcn_global_load_lds((const __attribute__((address_space(1))) void*)g,
                                   (__attribute__((address_space(3))) void*)l, 16, 0, 0);
}

// ---------------------------------------------------------------- cast fp32->bf16
__global__ void cast_all(const float* __restrict__ x, const float* __restrict__ wq,
                         const float* __restrict__ wk, const float* __restrict__ wv,
                         const float* __restrict__ wo,
                         u16* __restrict__ xb, u16* __restrict__ wqb,
                         u16* __restrict__ wkb, u16* __restrict__ wvb,
                         u16* __restrict__ wob) {
  const size_t stride = (size_t)gridDim.x * blockDim.x;
  for (size_t u = (size_t)blockIdx.x * blockDim.x + threadIdx.x; u < 12582912u; u += stride) {
    const float* in; u16* outp; size_t i;
    if (u < 2097152u)      { in = x;  outp = xb;  i = u; }
    else if (u < 6291456u) { in = wq; outp = wqb; i = u - 2097152u; }
    else if (u < 7340032u) { in = wk; outp = wkb; i = u - 6291456u; }
    else if (u < 8388608u) { in = wv; outp = wvb; i = u - 7340032u; }
    else                   { in = wo; outp = wob; i = u - 8388608u; }
    float4 f = ((const float4*)in)[i];
    ushort4 b;
    b.x = f2bf(f.x); b.y = f2bf(f.y); b.z = f2bf(f.z); b.w = f2bf(f.w);
    ((ushort4*)outp)[i] = b;
  }
}

// ---------------------------------------------------------------- 2-phase GEMM, BM=128, BN=64*NF
// C = A * B^T, bf16 row-major inputs. 4 waves (2x2), wave-tile 64 x 32*NF.
// BK=64. Double-buffered LDS: 2 x (A 16KB + B 8*NF KB) = 80 KB (NF=3) or
// 64 KB (NF=2) -> 2 blocks/CU. Grid 512 = 2/CU: cross-block TLP hides the
// per-K-tile __syncthreads drain (one block computes while the other waits).
// K-loop: STAGE(buf^1, t+1) -> ds_read+MFMA from buf -> __syncthreads (which
// emits vmcnt(0)+lgkmcnt(0)+barrier: staging complete AND reads consumed
// before anyone flips). 16B-unit XOR swizzle u^=(row&7) on the pre-swizzled
// global source (linear glds dest) + swizzled ds_read address -> 0 conflicts.
template<int UN>
__device__ __forceinline__ void stage_t(const u16* __restrict__ g, int ldg, int k0,
                                        u16* ldsp, int t) {
  const int wb = t & ~63;
#pragma unroll
  for (int j = 0; j < UN / 256; ++j) {
    const int U = j * 256 + t;
    const int row = U >> 3, u = U & 7;
    const int uu = u ^ (row & 7);
    glds16(g + (size_t)row * ldg + k0 + uu * 8, ldsp + (size_t)(j * 256 + wb) * 8);
  }
}

template<int NF, bool QKV3>
__global__ __launch_bounds__(256, 2)
void gemm2p(const u16* __restrict__ A, const u16* __restrict__ B,
            void* __restrict__ Cq, u16* __restrict__ Ck, u16* __restrict__ Cv,
            int K) {
  constexpr int BN = 64 * NF;
  constexpr int AT = 128 * 64;        // u16 per A tile (8192)
  constexpr int BT = BN * 64;         // u16 per B tile
  __shared__ u16 lds[2 * (AT + BT)];  // A0 @0, A1 @AT, B0 @2*AT, B1 @2*AT+BT
  const int t = threadIdx.x;
  const int l = t & 63, lr = l & 15, lg = l >> 4;
  const int wid = t >> 6, wm = wid >> 1, wn = wid & 1;
  const int m0 = blockIdx.y * 128, n0 = blockIdx.x * BN;
  const int KT = K >> 6;

  int axo[2];
  axo[0] = (lg ^ (lr & 7)) * 8;
  axo[1] = ((4 + lg) ^ (lr & 7)) * 8;

  const u16* Ab = A + (size_t)m0 * K;
  const u16* Bb = B + (size_t)n0 * K;

  f32x4 acc[4][2 * NF] = {};

  // prologue: stage tile 0 into buf 0
  stage_t<1024>(Ab, K, 0, &lds[0], t);
  stage_t<BT / 8>(Bb, K, 0, &lds[2 * AT], t);
  __syncthreads();

  int cur = 0;
#pragma unroll 1
  for (int tau = 0; tau < KT; ++tau) {
    const int kn = (tau + 1 < KT ? tau + 1 : KT - 1) * 64;
    // stage next tile into buf^1 (issued first so HBM latency hides under MFMA)
    stage_t<1024>(Ab, K, kn, &lds[(cur ^ 1) * AT], t);
    stage_t<BT / 8>(Bb, K, kn, &lds[2 * AT + (cur ^ 1) * BT], t);

    const int aBase = cur * AT;
    const int bBase = 2 * AT + cur * BT;

    bf16x8 af[4][2];
#pragma unroll
    for (int mf = 0; mf < 4; ++mf)
#pragma unroll
      for (int kk = 0; kk < 2; ++kk) {
        const int row = wm * 64 + mf * 16 + lr;
        af[mf][kk] = *(const bf16x8*)&lds[aBase + row * 64 + axo[kk] + ((row & 7) ? 0 : 0)];
      }
    // note: axo already encodes the kk*4+lg unit; apply row-XOR here:
#pragma unroll
    for (int mf = 0; mf < 4; ++mf)
#pragma unroll
      for (int kk = 0; kk < 2; ++kk) {
        const int row = wm * 64 + mf * 16 + lr;
        const int uu = ((kk * 4 + lg) ^ (row & 7)) * 8;
        af[mf][kk] = *(const bf16x8*)&lds[aBase + row * 64 + uu];
      }

#pragma unroll
    for (int n = 0; n < 2 * NF; ++n) {
      const int brow = wn * (32 * NF) + n * 16 + lr;
      const int u0 = ((0 * 4 + lg) ^ (brow & 7)) * 8;
      const int u1 = ((1 * 4 + lg) ^ (brow & 7)) * 8;
      bf16x8 b0 = *(const bf16x8*)&lds[bBase + brow * 64 + u0];
      bf16x8 b1 = *(const bf16x8*)&lds[bBase + brow * 64 + u1];
#pragma unroll
      for (int mf = 0; mf < 4; ++mf) {
        acc[mf][n] = __builtin_amdgcn_mfma_f32_16x16x32_bf16(af[mf][0], b0, acc[mf][n], 0, 0, 0);
        acc[mf][n] = __builtin_amdgcn_mfma_f32_16x16x32_bf16(af[mf][1], b1, acc[mf][n], 0, 0, 0);
      }
    }
    __syncthreads();
    cur ^= 1;
  }

  // epilogue; fragment cols are 16-aligned so QKV routing is per-fragment
#pragma unroll
  for (int mf = 0; mf < 4; ++mf) {
    const int row = m0 + wm * 64 + mf * 16 + lg * 4;
#pragma unroll
    for (int n = 0; n < 2 * NF; ++n) {
      const int gc = n0 + wn * (32 * NF) + n * 16 + lr;
#pragma unroll
      for (int r = 0; r < 4; ++r) {
        if constexpr (QKV3) {
          if (gc < 4096)
            ((u16*)Cq)[(size_t)(row + r) * 4096 + gc] = f2bf(acc[mf][n][r]);
          else if (gc < 5120)
            Ck[(size_t)(row + r) * 1024 + (gc - 4096)] = f2bf(acc[mf][n][r]);
          else
            Cv[(size_t)(row + r) * 1024 + (gc - 5120)] = f2bf(acc[mf][n][r]);
        } else {
          ((float*)Cq)[(size_t)(row + r) * 4096 + gc] = acc[mf][n][r];
        }
      }
    }
  }
}

// ---------------------------------------------------------------- RoPE (q then k)
__global__ void rope_all(u16* __restrict__ qd, u16* __restrict__ kd,
                         const float* __restrict__ cosb, const float* __restrict__ sinb,
                         const int* __restrict__ sidx) {
  const int u = blockIdx.x * blockDim.x + threadIdx.x;
  u16* base; int s, b;
  if (u < 1048576) {
    base = qd + (size_t)u * 8;
    s = u >> 9;
    b = u & 15;
  } else if (u < 1310720) {
    const int u2 = u - 1048576;
    base = kd + (size_t)u2 * 8;
    s = u2 >> 7;
    b = u2 & 15;
  } else return;
  const int pos = sidx[s];
  const float4 c  = *(const float4*)&cosb[pos * 64 + b * 4];
  const float4 sn = *(const float4*)&sinb[pos * 64 + b * 4];
  uint4 raw = *(uint4*)base;
  u16* pe = (u16*)&raw;
  const float cc[4] = {c.x, c.y, c.z, c.w};
  const float ss[4] = {sn.x, sn.y, sn.z, sn.w};
#pragma unroll
  for (int j = 0; j < 4; ++j) {
    const float xr = bf2f(pe[2 * j]), xi = bf2f(pe[2 * j + 1]);
    pe[2 * j]     = f2bf(xr * cc[j] - xi * ss[j]);
    pe[2 * j + 1] = f2bf(xr * ss[j] + xi * cc[j]);
  }
  *(uint4*)base = raw;
}

// ---------------------------------------------------------------- V transpose
__global__ void transpose_v(const u16* __restrict__ v, u16* __restrict__ vt) {
  __shared__ u16 tile[32][33];
  const int tx = threadIdx.x, ty = threadIdx.y;
  const int c0 = blockIdx.x * 32, s0 = blockIdx.y * 32;
#pragma unroll
  for (int j = 0; j < 32; j += 8)
    tile[ty + j][tx] = v[(size_t)(s0 + ty + j) * EKV + c0 + tx];
  __syncthreads();
#pragma unroll
  for (int j = 0; j < 32; j += 8)
    vt[(size_t)(c0 + ty + j) * S_LEN + s0 + tx] = tile[tx][ty + j];
}

// ---------------------------------------------------------------- flash attention
// Causal-paired blocks (p, 31-p): 33 KV-tiles per block, perfectly balanced.
__global__ __launch_bounds__(256, 2)
void attn_fwd(const u16* __restrict__ q, const u16* __restrict__ k,
              const u16* __restrict__ vt, u16* __restrict__ ao) {
  __shared__ u16 lK[64 * 128];
  __shared__ u16 lV[128 * 64];
  __shared__ u16 lP[4 * 16 * 72];
  const int t = threadIdx.x, w = t >> 6, l = t & 63;
  const int lr = l & 15, lg = l >> 4;
  const int wb = t & ~63;
  const int p = blockIdx.x, h = blockIdx.y;
  const int kvh = h >> 2;
  u16* lPw = &lP[w * (16 * 72)];

#pragma unroll 1
  for (int ph = 0; ph < 2; ++ph) {
    const int qt = ph ? (31 - p) : p;
    const int q0 = qt * 64 + w * 16;
    const int nt = qt + 1;

    bf16x8 qa[4];
#pragma unroll
    for (int kc = 0; kc < 4; ++kc)
      qa[kc] = *(const bf16x8*)&q[(size_t)(q0 + lr) * EQ + h * HDIM + kc * 32 + lg * 8];

    f32x4 o[8] = {};
    float mrun[4], lrun[4];
#pragma unroll
    for (int r = 0; r < 4; ++r) { mrun[r] = -1e30f; lrun[r] = 0.f; }

    for (int tk = 0; tk < nt; ++tk) {
      const int kv0 = tk * 64;
      __syncthreads();
#pragma unroll
      for (int hh = 0; hh < 4; ++hh) {
        const int f = hh * 256 + t;
        { const int row = f >> 4, u = f & 15, us = u ^ (row & 7);
          glds16(&k[(size_t)(kv0 + row) * EKV + kvh * HDIM + us * 8], &lK[(hh * 256 + wb) * 8]); }
        { const int row = f >> 3, u = f & 7, us = u ^ (row & 7);
          glds16(&vt[(size_t)(kvh * HDIM + row) * S_LEN + kv0 + us * 8], &lV[(hh * 256 + wb) * 8]); }
      }
      __syncthreads();

      f32x4 sc[4] = {};
#pragma unroll
      for (int n = 0; n < 4; ++n) {
#pragma unroll
        for (int kc = 0; kc < 4; ++kc) {
          const int row = n * 16 + lr;
          const int us = (kc * 4 + lg) ^ (row & 7);
          bf16x8 bk = *(const bf16x8*)&lK[row * 128 + us * 8];
          sc[n] = __builtin_amdgcn_mfma_f32_16x16x32_bf16(qa[kc], bk, sc[n], 0, 0, 0);
        }
      }

#pragma unroll
      for (int n = 0; n < 4; ++n) {
        const int kvc = kv0 + n * 16 + lr;
#pragma unroll
        for (int r = 0; r < 4; ++r) {
          const int qr = q0 + lg * 4 + r;
          const float v = sc[n][r] * SC_LOG2E;
          sc[n][r] = (kvc > qr) ? -1e30f : v;
        }
      }
#pragma unroll
      for (int r = 0; r < 4; ++r) {
        float v = fmaxf(fmaxf(sc[0][r], sc[1][r]), fmaxf(sc[2][r], sc[3][r]));
        v = fmaxf(v, __shfl_xor(v, 1));
        v = fmaxf(v, __shfl_xor(v, 2));
        v = fmaxf(v, __shfl_xor(v, 4));
        v = fmaxf(v, __shfl_xor(v, 8));
        const float mn = fmaxf(mrun[r], v);
        const float sf = __builtin_amdgcn_exp2f(mrun[r] - mn);
        mrun[r] = mn;
        float rs = 0.f;
#pragma unroll
        for (int n = 0; n < 4; ++n) {
          const float pv = __builtin_amdgcn_exp2f(sc[n][r] - mn);
          sc[n][r] = pv;
          rs += pv;
        }
        rs += __shfl_xor(rs, 1);
        rs += __shfl_xor(rs, 2);
        rs += __shfl_xor(rs, 4);
        rs += __shfl_xor(rs, 8);
        lrun[r] = lrun[r] * sf + rs;
#pragma unroll
        for (int nh = 0; nh < 8; ++nh) o[nh][r] *= sf;
      }
#pragma unroll
      for (int n = 0; n < 4; ++n)
#pragma unroll
        for (int r = 0; r < 4; ++r)
          lPw[(lg * 4 + r) * 72 + n * 16 + lr] = f2bf(sc[n][r]);

#pragma unroll
      for (int kc2 = 0; kc2 < 2; ++kc2) {
        bf16x8 pa = *(const bf16x8*)&lPw[lr * 72 + kc2 * 32 + lg * 8];
#pragma unroll
        for (int nh = 0; nh < 8; ++nh) {
          const int row = nh * 16 + lr;
          const int us = (kc2 * 4 + lg) ^ (row & 7);
          bf16x8 bv = *(const bf16x8*)&lV[row * 64 + us * 8];
          o[nh] = __builtin_amdgcn_mfma_f32_16x16x32_bf16(pa, bv, o[nh], 0, 0, 0);
        }
      }
    }

#pragma unroll
    for (int nh = 0; nh < 8; ++nh)
#pragma unroll
      for (int r = 0; r < 4; ++r) {
        const float val = o[nh][r] / lrun[r];
        ao[(size_t)(q0 + lg * 4 + r) * EQ + h * HDIM + nh * 16 + lr] = f2bf(val);
      }
  }
}

// ---------------------------------------------------------------- launch
extern "C" void kernel_launch(void* const* d_in, const int* in_sizes, int n_in,
                              void* d_out, int out_size, void* d_ws, size_t ws_size,
                              hipStream_t stream) {
  (void)in_sizes; (void)n_in; (void)out_size; (void)ws_size;
  const float* x    = (const float*)d_in[0];
  const float* wq   = (const float*)d_in[1];
  const float* wk   = (const float*)d_in[2];
  const float* wv   = (const float*)d_in[3];
  const float* wo   = (const float*)d_in[4];
  const float* cosb = (const float*)d_in[7];
  const float* sinb = (const float*)d_in[8];
  const int*   sidx = (const int*)d_in[10];
  float* out = (float*)d_out;

  // workspace layout; wqb/wkb/wvb are contiguous so B_qkv = [wq;wk;wv]
  u16* ws  = (u16*)d_ws;
  u16* xb  = ws;                                  // 2048*4096
  u16* wqb = xb  + (size_t)S_LEN * DM;            // 4096*4096
  u16* wkb = wqb + (size_t)EQ * DM;               // 1024*4096
  u16* wvb = wkb + (size_t)EKV * DM;              // 1024*4096
  u16* wob = wvb + (size_t)EKV * DM;              // 4096*4096
  u16* qb  = wob + (size_t)DM * EQ;               // 2048*4096
  u16* kb  = qb  + (size_t)S_LEN * EQ;            // 2048*1024
  u16* vb  = kb  + (size_t)S_LEN * EKV;           // 2048*1024
  u16* vtb = vb  + (size_t)S_LEN * EKV;           // 1024*2048
  u16* aob = vtb + (size_t)S_LEN * EKV;           // 2048*4096

  cast_all<<<2048, 256, 0, stream>>>(x, wq, wk, wv, wo, xb, wqb, wkb, wvb, wob);
  // fused QKV projection: B = [wq;wk;wv] (6144 x 4096), BM=128/BN=192 -> 32x16 = 512 blocks
  gemm2p<3, true><<<dim3(32, 16), 256, 0, stream>>>(xb, wqb, qb, kb, vb, DM);
  rope_all<<<5120, 256, 0, stream>>>(qb, kb, cosb, sinb, sidx);
  transpose_v<<<dim3(EKV / 32, S_LEN / 32), dim3(32, 8), 0, stream>>>(vb, vtb);
  attn_fwd<<<dim3(16, NH), 256, 0, stream>>>(qb, kb, vtb, aob);
  // O projection: BM=128/BN=128 -> 32x16 = 512 blocks
  gemm2p<2, false><<<dim3(32, 16), 256, 0, stream>>>(aob, wob, out, nullptr, nullptr, EQ);
}